// Round 1
// baseline (1216.545 us; speedup 1.0000x reference)
//
#include <hip/hip_runtime.h>
#include <cstdint>
#include <cstddef>

// Problem constants
#define BB  4
#define NN  32768
#define HH  256
#define SS  64
#define NHH 8
#define HDD 32

__device__ __forceinline__ float dot4(const float4 a, const float4 b) {
    return a.x * b.x + a.y * b.y + a.z * b.z + a.w * b.w;
}
__device__ __forceinline__ void fma4(float4& a, const float w, const float4 b) {
    a.x += w * b.x; a.y += w * b.y; a.z += w * b.z; a.w += w * b.w;
}

// ---------------------------------------------------------------------------
// K1: fused scores (x @ sq_w^T + sq_b) -> softmax -> W (global) -> pool partial
// grid: B * 128 blocks of 256 threads; each block does 256 rows (4 subtiles of 64)
// x read straight from global (L1/L2 hot, broadcast across lanes);
// LDS holds only sq_w k-chunk [64][64]p68 and the W tile [64][64]p68.
// ---------------------------------------------------------------------------
__global__ __launch_bounds__(256, 2)
void k1_score_pool(const float* __restrict__ x, const float* __restrict__ sq_w,
                   const float* __restrict__ sq_b, float* __restrict__ Wout,
                   float* __restrict__ partial)
{
    __shared__ __align__(16) float sw[SS * 68];   // sq_w chunk [slot][k] pad 68
    __shared__ __align__(16) float wt[64 * 68];   // W tile [row][slot] pad 68
    const int t  = threadIdx.x;
    const int b  = blockIdx.x >> 7;
    const int c  = blockIdx.x & 127;
    const int n0 = c * 256;
    const float* xb = x + (size_t)b * NN * HH;

    const int trw = t >> 4;   // score: rows {4*trw+i}
    const int tsw = t & 15;   // score: slots {tsw+16j}
    const int th2 = t >> 4;   // pool: h = th2*4 + 64*i + jj
    const int ts2 = t & 15;   // pool: slots {ts2+16j}

    float4 accp[4][4];        // pool accumulators [slot j][h-chunk i]
#pragma unroll
    for (int j = 0; j < 4; ++j)
#pragma unroll
        for (int i = 0; i < 4; ++i) accp[j][i] = make_float4(0.f, 0.f, 0.f, 0.f);

    float sb[4];
#pragma unroll
    for (int j = 0; j < 4; ++j) sb[j] = sq_b[tsw + 16 * j];

    for (int scnk = 0; scnk < 4; ++scnk) {
        const int r0 = n0 + scnk * 64;
        float sacc[4][4];
#pragma unroll
        for (int i = 0; i < 4; ++i)
#pragma unroll
            for (int j = 0; j < 4; ++j) sacc[i][j] = 0.f;

        for (int kc = 0; kc < 4; ++kc) {
            __syncthreads();
            // stage sq_w chunk: 64 slots x 64 k
#pragma unroll
            for (int ii = 0; ii < 4; ++ii) {
                int idx = ii * 256 + t;          // 0..1023
                int ssl = idx >> 4, q = idx & 15;
                float4 v = ((const float4*)(sq_w + ssl * HH + kc * 64))[q];
                ((float4*)(sw + ssl * 68))[q] = v;
            }
            __syncthreads();
#pragma unroll
            for (int kk = 0; kk < 64; kk += 4) {
                float4 xv[4], wv[4];
#pragma unroll
                for (int i = 0; i < 4; ++i)
                    xv[i] = *(const float4*)(xb + (size_t)(r0 + 4 * trw + i) * HH + kc * 64 + kk);
#pragma unroll
                for (int j = 0; j < 4; ++j)
                    wv[j] = *(const float4*)(sw + (tsw + 16 * j) * 68 + kk);
#pragma unroll
                for (int i = 0; i < 4; ++i)
#pragma unroll
                    for (int j = 0; j < 4; ++j) sacc[i][j] += dot4(xv[i], wv[j]);
            }
        }
        // softmax per row (64 slots spread over 16 lanes x 4 regs)
#pragma unroll
        for (int i = 0; i < 4; ++i) {
#pragma unroll
            for (int j = 0; j < 4; ++j) sacc[i][j] += sb[j];
            float m = fmaxf(fmaxf(sacc[i][0], sacc[i][1]), fmaxf(sacc[i][2], sacc[i][3]));
#pragma unroll
            for (int msk = 1; msk < 16; msk <<= 1) m = fmaxf(m, __shfl_xor(m, msk));
            float e[4], ssum = 0.f;
#pragma unroll
            for (int j = 0; j < 4; ++j) { e[j] = __expf(sacc[i][j] - m); ssum += e[j]; }
#pragma unroll
            for (int msk = 1; msk < 16; msk <<= 1) ssum += __shfl_xor(ssum, msk);
            const float inv = 1.f / ssum;
            const int row = 4 * trw + i;
            const size_t gro = ((size_t)b * NN + (size_t)(r0 + row)) * SS;
#pragma unroll
            for (int j = 0; j < 4; ++j) {
                float wv = e[j] * inv;
                wt[row * 68 + tsw + 16 * j] = wv;
                Wout[gro + tsw + 16 * j] = wv;
            }
        }
        __syncthreads();
        // pool phase: st_part[s][h] += W[r][s] * x[r][h]
#pragma unroll 4
        for (int r = 0; r < 64; ++r) {
            const float w0 = wt[r * 68 + ts2];
            const float w1 = wt[r * 68 + ts2 + 16];
            const float w2 = wt[r * 68 + ts2 + 32];
            const float w3 = wt[r * 68 + ts2 + 48];
            const float* xr = xb + (size_t)(r0 + r) * HH + th2 * 4;
#pragma unroll
            for (int i = 0; i < 4; ++i) {
                float4 xv = *(const float4*)(xr + 64 * i);
                fma4(accp[0][i], w0, xv);
                fma4(accp[1][i], w1, xv);
                fma4(accp[2][i], w2, xv);
                fma4(accp[3][i], w3, xv);
            }
        }
    }
    // write pool partial for this block
    float* pb = partial + ((size_t)(b * 128 + c) * SS) * HH;
#pragma unroll
    for (int j = 0; j < 4; ++j)
#pragma unroll
        for (int i = 0; i < 4; ++i)
            *((float4*)(pb + (ts2 + 16 * j) * HH + th2 * 4 + 64 * i)) = accp[j][i];
}

// ---------------------------------------------------------------------------
// K1c: reduce 128 pool partials -> st0 [B][S][H]
// ---------------------------------------------------------------------------
__global__ __launch_bounds__(256)
void k1c_reduce(const float* __restrict__ partial, float* __restrict__ st0)
{
    const int gid = blockIdx.x * 256 + threadIdx.x;  // 0..65535
    const int b = gid >> 14, rem = gid & 16383;
    const float* p = partial + (size_t)b * 128 * 16384 + rem;
    float s = 0.f;
#pragma unroll 8
    for (int c = 0; c < 128; ++c) s += p[(size_t)c * 16384];
    st0[gid] = s;
}

// ---------------------------------------------------------------------------
// MK1a: eidetic gate: st2 = st0 + sigmoid(st0 @ gw^T + gb) * eid_state
// grid 64 (one per slot), all 4 batches per block
// ---------------------------------------------------------------------------
__global__ __launch_bounds__(256)
void mk1a_gate(const float* __restrict__ st0, const float* __restrict__ eid_state,
               const float* __restrict__ gw, const float* __restrict__ gb,
               float* __restrict__ st2)
{
    __shared__ __align__(16) float srow[4][HH];
    const int s = blockIdx.x, t = threadIdx.x;
#pragma unroll
    for (int b = 0; b < 4; ++b) srow[b][t] = st0[(b * SS + s) * HH + t];
    __syncthreads();
    float acc[4] = {0.f, 0.f, 0.f, 0.f};
    const float4* wr = (const float4*)(gw + (size_t)t * HH);
    for (int k = 0; k < HH; k += 4) {
        float4 wv = wr[k >> 2];
#pragma unroll
        for (int b = 0; b < 4; ++b) acc[b] += dot4(*(const float4*)(&srow[b][k]), wv);
    }
    const float bias = gb[t];
    const float es = eid_state[s * HH + t];
#pragma unroll
    for (int b = 0; b < 4; ++b) {
        float gate = 1.f / (1.f + __expf(-(acc[b] + bias)));
        st2[(b * SS + s) * HH + t] = srow[b][t] + gate * es;
    }
}

// ---------------------------------------------------------------------------
// MK1b: qkv = st2 @ in_w^T + in_b ; grid 64*3 (slot, third), 4 batches/block
// ---------------------------------------------------------------------------
__global__ __launch_bounds__(256)
void mk1b_qkv(const float* __restrict__ st2, const float* __restrict__ in_w,
              const float* __restrict__ in_b, float* __restrict__ qkv)
{
    __shared__ __align__(16) float srow[4][HH];
    const int s = blockIdx.x / 3, third = blockIdx.x % 3;
    const int t = threadIdx.x;
#pragma unroll
    for (int b = 0; b < 4; ++b) srow[b][t] = st2[(b * SS + s) * HH + t];
    __syncthreads();
    const int o = third * 256 + t;
    float acc[4] = {0.f, 0.f, 0.f, 0.f};
    const float4* wr = (const float4*)(in_w + (size_t)o * HH);
    for (int k = 0; k < HH; k += 4) {
        float4 wv = wr[k >> 2];
#pragma unroll
        for (int b = 0; b < 4; ++b) acc[b] += dot4(*(const float4*)(&srow[b][k]), wv);
    }
    const float bias = in_b[o];
#pragma unroll
    for (int b = 0; b < 4; ++b) qkv[(b * SS + s) * 768 + o] = acc[b] + bias;
}

// ---------------------------------------------------------------------------
// MK2: multi-head attention over slots; grid 32 = (b, head), 64 threads (q slot)
// ---------------------------------------------------------------------------
__global__ __launch_bounds__(64)
void mk2_attn(const float* __restrict__ qkv, float* __restrict__ ao)
{
    __shared__ __align__(16) float Ks[SS][36], Vs[SS][36];
    const int b = blockIdx.x >> 3, nh = blockIdx.x & 7;
    const int qi = threadIdx.x;
    const float* base = qkv + (size_t)(b * SS + qi) * 768 + nh * HDD;
    float q[HDD];
#pragma unroll
    for (int d = 0; d < HDD; d += 4) {
        float4 v = *(const float4*)(base + d);
        q[d] = v.x; q[d + 1] = v.y; q[d + 2] = v.z; q[d + 3] = v.w;
        *(float4*)(&Ks[qi][d]) = *(const float4*)(base + 256 + d);
        *(float4*)(&Vs[qi][d]) = *(const float4*)(base + 512 + d);
    }
    __syncthreads();
    float sc[SS];
#pragma unroll
    for (int ki = 0; ki < SS; ++ki) {
        float a = 0.f;
#pragma unroll
        for (int d = 0; d < HDD; ++d) a += q[d] * Ks[ki][d];
        sc[ki] = a * 0.17677669529663687f;  // 1/sqrt(32)
    }
    float m = sc[0];
#pragma unroll
    for (int ki = 1; ki < SS; ++ki) m = fmaxf(m, sc[ki]);
    float ssum = 0.f;
#pragma unroll
    for (int ki = 0; ki < SS; ++ki) { sc[ki] = __expf(sc[ki] - m); ssum += sc[ki]; }
    const float inv = 1.f / ssum;
    float o[HDD];
#pragma unroll
    for (int d = 0; d < HDD; ++d) o[d] = 0.f;
#pragma unroll
    for (int ki = 0; ki < SS; ++ki) {
        const float p = sc[ki] * inv;
#pragma unroll
        for (int d = 0; d < HDD; ++d) o[d] += p * Vs[ki][d];
    }
    float* aob = ao + (size_t)(b * SS + qi) * HH + nh * HDD;
#pragma unroll
    for (int d = 0; d < HDD; d += 4)
        *(float4*)(aob + d) = make_float4(o[d], o[d + 1], o[d + 2], o[d + 3]);
}

// block-wide dual reduction (sum of v1 and v2 over 256 threads)
__device__ __forceinline__ void block_reduce_2(float& v1, float& v2, float* lds8)
{
#pragma unroll
    for (int m = 32; m; m >>= 1) { v1 += __shfl_xor(v1, m); v2 += __shfl_xor(v2, m); }
    const int w = threadIdx.x >> 6;
    __syncthreads();
    if ((threadIdx.x & 63) == 0) { lds8[w] = v1; lds8[4 + w] = v2; }
    __syncthreads();
    v1 = lds8[0] + lds8[1] + lds8[2] + lds8[3];
    v2 = lds8[4] + lds8[5] + lds8[6] + lds8[7];
}

// ---------------------------------------------------------------------------
// MK3: out-proj + residual + LayerNorm1 -> st3 ; grid 64 (slot)
// ---------------------------------------------------------------------------
__global__ __launch_bounds__(256)
void mk3_outln(const float* __restrict__ ao, const float* __restrict__ out_w,
               const float* __restrict__ out_b, const float* __restrict__ st2,
               const float* __restrict__ n1g, const float* __restrict__ n1b,
               float* __restrict__ st3)
{
    __shared__ __align__(16) float arow[4][HH];
    __shared__ float red[8];
    const int s = blockIdx.x, t = threadIdx.x;
#pragma unroll
    for (int b = 0; b < 4; ++b) arow[b][t] = ao[(b * SS + s) * HH + t];
    __syncthreads();
    float acc[4] = {0.f, 0.f, 0.f, 0.f};
    const float4* wr = (const float4*)(out_w + (size_t)t * HH);
    for (int k = 0; k < HH; k += 4) {
        float4 wv = wr[k >> 2];
#pragma unroll
        for (int b = 0; b < 4; ++b) acc[b] += dot4(*(const float4*)(&arow[b][k]), wv);
    }
    const float ob = out_b[t], g = n1g[t], bt = n1b[t];
#pragma unroll
    for (int b = 0; b < 4; ++b) {
        const float y = st2[(b * SS + s) * HH + t] + acc[b] + ob;
        float s1 = y, s2 = y * y;
        block_reduce_2(s1, s2, red);
        const float mu = s1 * (1.f / HH);
        const float var = s2 * (1.f / HH) - mu * mu;
        const float r = rsqrtf(var + 1e-5f);
        st3[(b * SS + s) * HH + t] = (y - mu) * r * g + bt;
    }
}

// ---------------------------------------------------------------------------
// MK4: FFN1 + exact GELU -> h1 ; grid 64*4 (slot, quarter of 1024)
// ---------------------------------------------------------------------------
__global__ __launch_bounds__(256)
void mk4_ffn1(const float* __restrict__ st3, const float* __restrict__ f1w,
              const float* __restrict__ f1b, float* __restrict__ h1)
{
    __shared__ __align__(16) float srow[4][HH];
    const int s = blockIdx.x >> 2, quarter = blockIdx.x & 3;
    const int t = threadIdx.x;
#pragma unroll
    for (int b = 0; b < 4; ++b) srow[b][t] = st3[(b * SS + s) * HH + t];
    __syncthreads();
    const int o = quarter * 256 + t;
    float acc[4] = {0.f, 0.f, 0.f, 0.f};
    const float4* wr = (const float4*)(f1w + (size_t)o * HH);
    for (int k = 0; k < HH; k += 4) {
        float4 wv = wr[k >> 2];
#pragma unroll
        for (int b = 0; b < 4; ++b) acc[b] += dot4(*(const float4*)(&srow[b][k]), wv);
    }
    const float bias = f1b[o];
#pragma unroll
    for (int b = 0; b < 4; ++b) {
        const float u = acc[b] + bias;
        h1[(b * SS + s) * 1024 + o] = 0.5f * u * (1.f + erff(u * 0.70710678118654752f));
    }
}

// ---------------------------------------------------------------------------
// MK5: FFN2 + residual + LayerNorm2 -> st4 ; grid 64 (slot)
// ---------------------------------------------------------------------------
__global__ __launch_bounds__(256)
void mk5_ffn2(const float* __restrict__ h1, const float* __restrict__ f2w,
              const float* __restrict__ f2b, const float* __restrict__ st3,
              const float* __restrict__ n2g, const float* __restrict__ n2b,
              float* __restrict__ st4)
{
    __shared__ __align__(16) float hrow[4][1024];
    __shared__ float red[8];
    const int s = blockIdx.x, t = threadIdx.x;
#pragma unroll
    for (int b = 0; b < 4; ++b)
        for (int idx = t; idx < 1024; idx += 256) hrow[b][idx] = h1[(b * SS + s) * 1024 + idx];
    __syncthreads();
    float acc[4] = {0.f, 0.f, 0.f, 0.f};
    const float4* wr = (const float4*)(f2w + (size_t)t * 1024);
    for (int k = 0; k < 1024; k += 4) {
        float4 wv = wr[k >> 2];
#pragma unroll
        for (int b = 0; b < 4; ++b) acc[b] += dot4(*(const float4*)(&hrow[b][k]), wv);
    }
    const float fb = f2b[t], g = n2g[t], bt = n2b[t];
#pragma unroll
    for (int b = 0; b < 4; ++b) {
        const float y = st3[(b * SS + s) * HH + t] + acc[b] + fb;
        float s1 = y, s2 = y * y;
        block_reduce_2(s1, s2, red);
        const float mu = s1 * (1.f / HH);
        const float var = s2 * (1.f / HH) - mu * mu;
        const float r = rsqrtf(var + 1e-5f);
        st4[(b * SS + s) * HH + t] = (y - mu) * r * g + bt;
    }
}

// ---------------------------------------------------------------------------
// K3: decode: out = W @ st4 + x ; grid B*1024 blocks (32 rows each)
// ---------------------------------------------------------------------------
__global__ __launch_bounds__(256, 4)
void k3_decode(const float* __restrict__ Wm, const float* __restrict__ st4,
               const float* __restrict__ x, float* __restrict__ out)
{
    __shared__ __align__(16) float wt3[32 * 68];
    const int t = threadIdx.x;
    const int b = blockIdx.x >> 10;
    const int c = blockIdx.x & 1023;
    const int n0 = c * 32;
#pragma unroll
    for (int ii = 0; ii < 8; ++ii) {
        int idx = ii * 256 + t;  // 0..2047
        int r = idx >> 6, sl = idx & 63;
        wt3[r * 68 + sl] = Wm[((size_t)b * NN + n0 + r) * SS + sl];
    }
    __syncthreads();
    const int tr = t >> 4, th = t & 15;
    const float* sbase = st4 + (size_t)b * SS * HH + th * 4;
    float4 acc[2][4];
#pragma unroll
    for (int i2 = 0; i2 < 2; ++i2)
#pragma unroll
        for (int i = 0; i < 4; ++i) acc[i2][i] = make_float4(0.f, 0.f, 0.f, 0.f);
    for (int sl = 0; sl < SS; ++sl) {
        const float w0 = wt3[(2 * tr) * 68 + sl];
        const float w1 = wt3[(2 * tr + 1) * 68 + sl];
        const float* sr = sbase + sl * HH;
#pragma unroll
        for (int i = 0; i < 4; ++i) {
            float4 sv = *(const float4*)(sr + 64 * i);
            fma4(acc[0][i], w0, sv);
            fma4(acc[1][i], w1, sv);
        }
    }
#pragma unroll
    for (int i2 = 0; i2 < 2; ++i2) {
        const size_t ro = ((size_t)b * NN + n0 + 2 * tr + i2) * HH + th * 4;
#pragma unroll
        for (int i = 0; i < 4; ++i) {
            float4 xv = *(const float4*)(x + ro + 64 * i);
            float4 a = acc[i2][i];
            a.x += xv.x; a.y += xv.y; a.z += xv.z; a.w += xv.w;
            *(float4*)(out + ro + 64 * i) = a;
        }
    }
}

// ---------------------------------------------------------------------------
extern "C" void kernel_launch(void* const* d_in, const int* in_sizes, int n_in,
                              void* d_out, int out_size, void* d_ws, size_t ws_size,
                              hipStream_t stream)
{
    const float* x         = (const float*)d_in[0];
    const float* sq_w      = (const float*)d_in[1];
    const float* sq_b      = (const float*)d_in[2];
    const float* eid_state = (const float*)d_in[3];
    const float* eid_gw    = (const float*)d_in[4];
    const float* eid_gb    = (const float*)d_in[5];
    const float* in_w      = (const float*)d_in[6];
    const float* in_b      = (const float*)d_in[7];
    const float* out_w     = (const float*)d_in[8];
    const float* out_b     = (const float*)d_in[9];
    const float* n1_g      = (const float*)d_in[10];
    const float* n1_b      = (const float*)d_in[11];
    const float* n2_g      = (const float*)d_in[12];
    const float* n2_b      = (const float*)d_in[13];
    const float* f1_w      = (const float*)d_in[14];
    const float* f1_b      = (const float*)d_in[15];
    const float* f2_w      = (const float*)d_in[16];
    const float* f2_b      = (const float*)d_in[17];

    float* ws      = (float*)d_ws;
    float* Wm      = ws;                       // [B][N][S]      8388608
    float* partial = Wm + 8388608;             // [B][128][S][H] 8388608
    float* st0     = partial + 8388608;        // [B][S][H]      65536
    float* st2     = st0 + 65536;
    float* qkv     = st2 + 65536;              // [B][S][768]    196608
    float* ao      = qkv + 196608;             // [B][S][H]      65536
    float* st3     = ao + 65536;
    float* h1      = st3 + 65536;              // [B][S][1024]   262144
    float* st4     = h1 + 262144;              // [B][S][H]      65536
    float* out     = (float*)d_out;

    hipLaunchKernelGGL(k1_score_pool, dim3(BB * 128), dim3(256), 0, stream,
                       x, sq_w, sq_b, Wm, partial);
    hipLaunchKernelGGL(k1c_reduce, dim3(256), dim3(256), 0, stream, partial, st0);
    hipLaunchKernelGGL(mk1a_gate, dim3(SS), dim3(256), 0, stream,
                       st0, eid_state, eid_gw, eid_gb, st2);
    hipLaunchKernelGGL(mk1b_qkv, dim3(SS * 3), dim3(256), 0, stream,
                       st2, in_w, in_b, qkv);
    hipLaunchKernelGGL(mk2_attn, dim3(BB * NHH), dim3(64), 0, stream, qkv, ao);
    hipLaunchKernelGGL(mk3_outln, dim3(SS), dim3(256), 0, stream,
                       ao, out_w, out_b, st2, n1_g, n1_b, st3);
    hipLaunchKernelGGL(mk4_ffn1, dim3(SS * 4), dim3(256), 0, stream,
                       st3, f1_w, f1_b, h1);
    hipLaunchKernelGGL(mk5_ffn2, dim3(SS), dim3(256), 0, stream,
                       h1, f2_w, f2_b, st3, n2_g, n2_b, st4);
    hipLaunchKernelGGL(k3_decode, dim3(BB * 1024), dim3(256), 0, stream,
                       Wm, st4, x, out);
}

// Round 2
// 493.119 us; speedup vs baseline: 2.4670x; 2.4670x over previous
//
#include <hip/hip_runtime.h>
#include <cstdint>
#include <cstddef>

// Problem constants
#define BB  4
#define NN  32768
#define HH  256
#define SS  64
#define NHH 8
#define HDD 32

typedef __attribute__((ext_vector_type(8))) short s16x8;
typedef __attribute__((ext_vector_type(4))) float f32x4;

__device__ __forceinline__ float dot4(const float4 a, const float4 b) {
    return a.x * b.x + a.y * b.y + a.z * b.z + a.w * b.w;
}

// fp32 -> bf16 (RTNE), returned in low 16 bits
__device__ __forceinline__ unsigned bf16r1(float f) {
    unsigned u = __float_as_uint(f);
    u += 0x7FFFu + ((u >> 16) & 1u);
    return u >> 16;
}
__device__ __forceinline__ unsigned bf16pk(float lo, float hi) {
    return bf16r1(lo) | (bf16r1(hi) << 16);
}

// ---------------------------------------------------------------------------
// K1a: scores = x @ sq_w^T + sq_b -> softmax -> W (bf16, global)
// MFMA 16x16x32 bf16. grid = B * 256 (128 tokens/block, 32/wave).
// A-frags: direct from global fp32 (cvt in regs). B-frags: sq_w bf16 in LDS.
// C-layout (verified m89): col = lane&15, row = (lane>>4)*4 + reg.
// ---------------------------------------------------------------------------
__global__ __launch_bounds__(256, 4)
void k1a_scores(const float* __restrict__ x, const float* __restrict__ sq_w,
                const float* __restrict__ sq_b, unsigned short* __restrict__ Wb)
{
    __shared__ unsigned sw[64 * 132];  // sq_w bf16-packed [s][k/2], stride 132 dwords
    const int t = threadIdx.x;
    {
        const int r = t >> 2, q = t & 3;
        const float4* src = (const float4*)(sq_w + r * HH + q * 64);
        unsigned* dst = sw + r * 132 + q * 32;
#pragma unroll
        for (int i = 0; i < 16; ++i) {
            float4 v = src[i];
            dst[2 * i]     = bf16pk(v.x, v.y);
            dst[2 * i + 1] = bf16pk(v.z, v.w);
        }
    }
    const int lane = t & 63, w = t >> 6;
    const int n16 = lane & 15, quad = lane >> 4;
    const int b = blockIdx.x >> 8;
    const int tok0 = (blockIdx.x & 255) * 128 + w * 32;
    const float* xb = x + ((size_t)b * NN + tok0) * HH;

    f32x4 acc[2][4];
#pragma unroll
    for (int mt = 0; mt < 2; ++mt)
#pragma unroll
        for (int nt = 0; nt < 4; ++nt) acc[mt][nt] = (f32x4)(0.f);

    __syncthreads();

    for (int kc = 0; kc < 8; ++kc) {
        union { unsigned u[4]; s16x8 s; } af[2];
#pragma unroll
        for (int mt = 0; mt < 2; ++mt) {
            const float* ap = xb + (size_t)(mt * 16 + n16) * HH + kc * 32 + quad * 8;
            float4 v0 = ((const float4*)ap)[0];
            float4 v1 = ((const float4*)ap)[1];
            af[mt].u[0] = bf16pk(v0.x, v0.y);
            af[mt].u[1] = bf16pk(v0.z, v0.w);
            af[mt].u[2] = bf16pk(v1.x, v1.y);
            af[mt].u[3] = bf16pk(v1.z, v1.w);
        }
#pragma unroll
        for (int nt = 0; nt < 4; ++nt) {
            union { uint4 u; s16x8 s; } bf;
            bf.u = *((const uint4*)(sw + (nt * 16 + n16) * 132 + kc * 16 + quad * 4));
#pragma unroll
            for (int mt = 0; mt < 2; ++mt)
                acc[mt][nt] = __builtin_amdgcn_mfma_f32_16x16x32_bf16(af[mt].s, bf.s, acc[mt][nt], 0, 0, 0);
        }
    }

    const float sb0 = sq_b[n16], sb1 = sq_b[16 + n16], sb2 = sq_b[32 + n16], sb3 = sq_b[48 + n16];
#pragma unroll
    for (int mt = 0; mt < 2; ++mt) {
#pragma unroll
        for (int r = 0; r < 4; ++r) {
            float v0 = acc[mt][0][r] + sb0;
            float v1 = acc[mt][1][r] + sb1;
            float v2 = acc[mt][2][r] + sb2;
            float v3 = acc[mt][3][r] + sb3;
            float m = fmaxf(fmaxf(v0, v1), fmaxf(v2, v3));
#pragma unroll
            for (int msk = 1; msk < 16; msk <<= 1) m = fmaxf(m, __shfl_xor(m, msk));
            float e0 = __expf(v0 - m), e1 = __expf(v1 - m), e2 = __expf(v2 - m), e3 = __expf(v3 - m);
            float s = e0 + e1 + e2 + e3;
#pragma unroll
            for (int msk = 1; msk < 16; msk <<= 1) s += __shfl_xor(s, msk);
            const float inv = 1.f / s;
            unsigned short* wp = Wb + ((size_t)b * NN + tok0 + mt * 16 + quad * 4 + r) * SS;
            wp[n16]      = (unsigned short)bf16r1(e0 * inv);
            wp[16 + n16] = (unsigned short)bf16r1(e1 * inv);
            wp[32 + n16] = (unsigned short)bf16r1(e2 * inv);
            wp[48 + n16] = (unsigned short)bf16r1(e3 * inv);
        }
    }
}

// ---------------------------------------------------------------------------
// K1b: pool partial[s][h] = sum_t W[t][s]*x[t][h] over 256-token chunk.
// MFMA with both operands token-contiguous via LDS transpose (bf16 pairs).
// grid = B * 128 chunks. Wave w -> s-tile w*16.. ; nt = 16 h-tiles.
// ---------------------------------------------------------------------------
__global__ __launch_bounds__(256, 2)
void k1b_pool(const float* __restrict__ x, const unsigned short* __restrict__ Wb,
              float* __restrict__ partial)
{
    __shared__ unsigned xt[256 * 20];  // x^T bf16 pairs [h][tokpair], stride 20
    __shared__ unsigned wt[64 * 20];   // W^T bf16 pairs [s][tokpair]
    const int t = threadIdx.x;
    const int lane = t & 63, w = t >> 6;
    const int n16 = lane & 15, quad = lane >> 4;
    const int b = blockIdx.x >> 7;
    const int c = blockIdx.x & 127;
    const float* xb = x + (size_t)b * NN * HH;
    const unsigned short* wbb = Wb + (size_t)b * NN * SS;

    const int sp = t & 15;   // token-pair index (0..15 -> 32 tokens)
    const int shb = t >> 4;  // h-block (x) / slot-group (W)

    f32x4 acc[16];
#pragma unroll
    for (int nt = 0; nt < 16; ++nt) acc[nt] = (f32x4)(0.f);

    for (int kc = 0; kc < 8; ++kc) {
        const int tk0 = c * 256 + kc * 32;
        __syncthreads();
        {   // stage x^T: 32 tokens x 256 h
            const float* r0 = xb + (size_t)(tk0 + 2 * sp) * HH + shb * 16;
            const float* r1 = r0 + HH;
#pragma unroll
            for (int i = 0; i < 4; ++i) {
                float4 a = ((const float4*)r0)[i];
                float4 bq = ((const float4*)r1)[i];
                unsigned* d = xt + (shb * 16 + i * 4) * 20 + sp;
                d[0]  = bf16pk(a.x, bq.x);
                d[20] = bf16pk(a.y, bq.y);
                d[40] = bf16pk(a.z, bq.z);
                d[60] = bf16pk(a.w, bq.w);
            }
        }
        {   // stage W^T: 32 tokens x 64 s
            const unsigned short* w0 = wbb + (size_t)(tk0 + 2 * sp) * SS + shb * 4;
            const unsigned short* w1 = w0 + SS;
            ushort4 a = *((const ushort4*)w0);
            ushort4 bq = *((const ushort4*)w1);
            unsigned* d = wt + (shb * 4) * 20 + sp;
            d[0]  = (unsigned)a.x | ((unsigned)bq.x << 16);
            d[20] = (unsigned)a.y | ((unsigned)bq.y << 16);
            d[40] = (unsigned)a.z | ((unsigned)bq.z << 16);
            d[60] = (unsigned)a.w | ((unsigned)bq.w << 16);
        }
        __syncthreads();
        union { uint4 u; s16x8 s; } av;
        av.u = *((const uint4*)(wt + (w * 16 + n16) * 20 + quad * 4));
#pragma unroll
        for (int nt = 0; nt < 16; ++nt) {
            union { uint4 u; s16x8 s; } bv;
            bv.u = *((const uint4*)(xt + (nt * 16 + n16) * 20 + quad * 4));
            acc[nt] = __builtin_amdgcn_mfma_f32_16x16x32_bf16(av.s, bv.s, acc[nt], 0, 0, 0);
        }
    }
    float* pb = partial + ((size_t)(b * 128 + c) * SS) * HH;
#pragma unroll
    for (int nt = 0; nt < 16; ++nt) {
#pragma unroll
        for (int r = 0; r < 4; ++r)
            pb[(size_t)(w * 16 + quad * 4 + r) * HH + nt * 16 + n16] = acc[nt][r];
    }
}

// ---------------------------------------------------------------------------
// K1c: reduce 128 pool partials -> st0 [B][S][H]
// ---------------------------------------------------------------------------
__global__ __launch_bounds__(256)
void k1c_reduce(const float* __restrict__ partial, float* __restrict__ st0)
{
    const int gid = blockIdx.x * 256 + threadIdx.x;  // 0..65535
    const int b = gid >> 14, rem = gid & 16383;
    const float* p = partial + (size_t)b * 128 * 16384 + rem;
    float s = 0.f;
#pragma unroll 8
    for (int c = 0; c < 128; ++c) s += p[(size_t)c * 16384];
    st0[gid] = s;
}

// ---------------------------------------------------------------------------
// MK1a: eidetic gate: st2 = st0 + sigmoid(st0 @ gw^T + gb) * eid_state
// ---------------------------------------------------------------------------
__global__ __launch_bounds__(256)
void mk1a_gate(const float* __restrict__ st0, const float* __restrict__ eid_state,
               const float* __restrict__ gw, const float* __restrict__ gb,
               float* __restrict__ st2)
{
    __shared__ __align__(16) float srow[4][HH];
    const int s = blockIdx.x, t = threadIdx.x;
#pragma unroll
    for (int b = 0; b < 4; ++b) srow[b][t] = st0[(b * SS + s) * HH + t];
    __syncthreads();
    float acc[4] = {0.f, 0.f, 0.f, 0.f};
    const float4* wr = (const float4*)(gw + (size_t)t * HH);
    for (int k = 0; k < HH; k += 4) {
        float4 wv = wr[k >> 2];
#pragma unroll
        for (int b = 0; b < 4; ++b) acc[b] += dot4(*(const float4*)(&srow[b][k]), wv);
    }
    const float bias = gb[t];
    const float es = eid_state[s * HH + t];
#pragma unroll
    for (int b = 0; b < 4; ++b) {
        float gate = 1.f / (1.f + __expf(-(acc[b] + bias)));
        st2[(b * SS + s) * HH + t] = srow[b][t] + gate * es;
    }
}

// ---------------------------------------------------------------------------
// MK1b: qkv = st2 @ in_w^T + in_b
// ---------------------------------------------------------------------------
__global__ __launch_bounds__(256)
void mk1b_qkv(const float* __restrict__ st2, const float* __restrict__ in_w,
              const float* __restrict__ in_b, float* __restrict__ qkv)
{
    __shared__ __align__(16) float srow[4][HH];
    const int s = blockIdx.x / 3, third = blockIdx.x % 3;
    const int t = threadIdx.x;
#pragma unroll
    for (int b = 0; b < 4; ++b) srow[b][t] = st2[(b * SS + s) * HH + t];
    __syncthreads();
    const int o = third * 256 + t;
    float acc[4] = {0.f, 0.f, 0.f, 0.f};
    const float4* wr = (const float4*)(in_w + (size_t)o * HH);
    for (int k = 0; k < HH; k += 4) {
        float4 wv = wr[k >> 2];
#pragma unroll
        for (int b = 0; b < 4; ++b) acc[b] += dot4(*(const float4*)(&srow[b][k]), wv);
    }
    const float bias = in_b[o];
#pragma unroll
    for (int b = 0; b < 4; ++b) qkv[(b * SS + s) * 768 + o] = acc[b] + bias;
}

// ---------------------------------------------------------------------------
// MK2: multi-head attention over slots
// ---------------------------------------------------------------------------
__global__ __launch_bounds__(64)
void mk2_attn(const float* __restrict__ qkv, float* __restrict__ ao)
{
    __shared__ __align__(16) float Ks[SS][36], Vs[SS][36];
    const int b = blockIdx.x >> 3, nh = blockIdx.x & 7;
    const int qi = threadIdx.x;
    const float* base = qkv + (size_t)(b * SS + qi) * 768 + nh * HDD;
    float q[HDD];
#pragma unroll
    for (int d = 0; d < HDD; d += 4) {
        float4 v = *(const float4*)(base + d);
        q[d] = v.x; q[d + 1] = v.y; q[d + 2] = v.z; q[d + 3] = v.w;
        *(float4*)(&Ks[qi][d]) = *(const float4*)(base + 256 + d);
        *(float4*)(&Vs[qi][d]) = *(const float4*)(base + 512 + d);
    }
    __syncthreads();
    float sc[SS];
#pragma unroll
    for (int ki = 0; ki < SS; ++ki) {
        float a = 0.f;
#pragma unroll
        for (int d = 0; d < HDD; ++d) a += q[d] * Ks[ki][d];
        sc[ki] = a * 0.17677669529663687f;
    }
    float m = sc[0];
#pragma unroll
    for (int ki = 1; ki < SS; ++ki) m = fmaxf(m, sc[ki]);
    float ssum = 0.f;
#pragma unroll
    for (int ki = 0; ki < SS; ++ki) { sc[ki] = __expf(sc[ki] - m); ssum += sc[ki]; }
    const float inv = 1.f / ssum;
    float o[HDD];
#pragma unroll
    for (int d = 0; d < HDD; ++d) o[d] = 0.f;
#pragma unroll
    for (int ki = 0; ki < SS; ++ki) {
        const float p = sc[ki] * inv;
#pragma unroll
        for (int d = 0; d < HDD; ++d) o[d] += p * Vs[ki][d];
    }
    float* aob = ao + (size_t)(b * SS + qi) * HH + nh * HDD;
#pragma unroll
    for (int d = 0; d < HDD; d += 4)
        *(float4*)(aob + d) = make_float4(o[d], o[d + 1], o[d + 2], o[d + 3]);
}

__device__ __forceinline__ void block_reduce_2(float& v1, float& v2, float* lds8)
{
#pragma unroll
    for (int m = 32; m; m >>= 1) { v1 += __shfl_xor(v1, m); v2 += __shfl_xor(v2, m); }
    const int w = threadIdx.x >> 6;
    __syncthreads();
    if ((threadIdx.x & 63) == 0) { lds8[w] = v1; lds8[4 + w] = v2; }
    __syncthreads();
    v1 = lds8[0] + lds8[1] + lds8[2] + lds8[3];
    v2 = lds8[4] + lds8[5] + lds8[6] + lds8[7];
}

// ---------------------------------------------------------------------------
// MK3: out-proj + residual + LayerNorm1 -> st3
// ---------------------------------------------------------------------------
__global__ __launch_bounds__(256)
void mk3_outln(const float* __restrict__ ao, const float* __restrict__ out_w,
               const float* __restrict__ out_b, const float* __restrict__ st2,
               const float* __restrict__ n1g, const float* __restrict__ n1b,
               float* __restrict__ st3)
{
    __shared__ __align__(16) float arow[4][HH];
    __shared__ float red[8];
    const int s = blockIdx.x, t = threadIdx.x;
#pragma unroll
    for (int b = 0; b < 4; ++b) arow[b][t] = ao[(b * SS + s) * HH + t];
    __syncthreads();
    float acc[4] = {0.f, 0.f, 0.f, 0.f};
    const float4* wr = (const float4*)(out_w + (size_t)t * HH);
    for (int k = 0; k < HH; k += 4) {
        float4 wv = wr[k >> 2];
#pragma unroll
        for (int b = 0; b < 4; ++b) acc[b] += dot4(*(const float4*)(&arow[b][k]), wv);
    }
    const float ob = out_b[t], g = n1g[t], bt = n1b[t];
#pragma unroll
    for (int b = 0; b < 4; ++b) {
        const float y = st2[(b * SS + s) * HH + t] + acc[b] + ob;
        float s1 = y, s2 = y * y;
        block_reduce_2(s1, s2, red);
        const float mu = s1 * (1.f / HH);
        const float var = s2 * (1.f / HH) - mu * mu;
        const float r = rsqrtf(var + 1e-5f);
        st3[(b * SS + s) * HH + t] = (y - mu) * r * g + bt;
    }
}

// ---------------------------------------------------------------------------
// MK4: FFN1 + exact GELU -> h1
// ---------------------------------------------------------------------------
__global__ __launch_bounds__(256)
void mk4_ffn1(const float* __restrict__ st3, const float* __restrict__ f1w,
              const float* __restrict__ f1b, float* __restrict__ h1)
{
    __shared__ __align__(16) float srow[4][HH];
    const int s = blockIdx.x >> 2, quarter = blockIdx.x & 3;
    const int t = threadIdx.x;
#pragma unroll
    for (int b = 0; b < 4; ++b) srow[b][t] = st3[(b * SS + s) * HH + t];
    __syncthreads();
    const int o = quarter * 256 + t;
    float acc[4] = {0.f, 0.f, 0.f, 0.f};
    const float4* wr = (const float4*)(f1w + (size_t)o * HH);
    for (int k = 0; k < HH; k += 4) {
        float4 wv = wr[k >> 2];
#pragma unroll
        for (int b = 0; b < 4; ++b) acc[b] += dot4(*(const float4*)(&srow[b][k]), wv);
    }
    const float bias = f1b[o];
#pragma unroll
    for (int b = 0; b < 4; ++b) {
        const float u = acc[b] + bias;
        h1[(b * SS + s) * 1024 + o] = 0.5f * u * (1.f + erff(u * 0.70710678118654752f));
    }
}

// ---------------------------------------------------------------------------
// MK5: FFN2 + residual + LayerNorm2 -> st4
// ---------------------------------------------------------------------------
__global__ __launch_bounds__(256)
void mk5_ffn2(const float* __restrict__ h1, const float* __restrict__ f2w,
              const float* __restrict__ f2b, const float* __restrict__ st3,
              const float* __restrict__ n2g, const float* __restrict__ n2b,
              float* __restrict__ st4)
{
    __shared__ __align__(16) float hrow[4][1024];
    __shared__ float red[8];
    const int s = blockIdx.x, t = threadIdx.x;
#pragma unroll
    for (int b = 0; b < 4; ++b)
        for (int idx = t; idx < 1024; idx += 256) hrow[b][idx] = h1[(b * SS + s) * 1024 + idx];
    __syncthreads();
    float acc[4] = {0.f, 0.f, 0.f, 0.f};
    const float4* wr = (const float4*)(f2w + (size_t)t * 1024);
    for (int k = 0; k < 1024; k += 4) {
        float4 wv = wr[k >> 2];
#pragma unroll
        for (int b = 0; b < 4; ++b) acc[b] += dot4(*(const float4*)(&hrow[b][k]), wv);
    }
    const float fb = f2b[t], g = n2g[t], bt = n2b[t];
#pragma unroll
    for (int b = 0; b < 4; ++b) {
        const float y = st3[(b * SS + s) * HH + t] + acc[b] + fb;
        float s1 = y, s2 = y * y;
        block_reduce_2(s1, s2, red);
        const float mu = s1 * (1.f / HH);
        const float var = s2 * (1.f / HH) - mu * mu;
        const float r = rsqrtf(var + 1e-5f);
        st4[(b * SS + s) * HH + t] = (y - mu) * r * g + bt;
    }
}

// ---------------------------------------------------------------------------
// K3: decode: out = W @ st4 + x via MFMA. grid = B * 512 (64 tokens/block).
// A = W rows (bf16, k=slot contiguous). B = st4^T bf16-pairs in LDS.
// ---------------------------------------------------------------------------
__global__ __launch_bounds__(256, 3)
void k3_decode(const unsigned short* __restrict__ Wb, const float* __restrict__ st4,
               const float* __restrict__ x, float* __restrict__ out)
{
    __shared__ unsigned s4t[256 * 36];  // st4^T bf16 pairs [h][s-pair], stride 36
    const int t = threadIdx.x;
    const int lane = t & 63, w = t >> 6;
    const int n16 = lane & 15, quad = lane >> 4;
    const int b = blockIdx.x >> 9;
    const int c = blockIdx.x & 511;
    const int tok0 = c * 64;
    {
        const int sp = t & 31, hb = t >> 5;   // 32 slot-pairs, 8 h-blocks of 32
        const float* r0 = st4 + (size_t)(b * SS + 2 * sp) * HH + hb * 32;
        const float* r1 = r0 + HH;
#pragma unroll
        for (int i = 0; i < 8; ++i) {
            float4 a = ((const float4*)r0)[i];
            float4 bq = ((const float4*)r1)[i];
            unsigned* d = s4t + (hb * 32 + i * 4) * 36 + sp;
            d[0]   = bf16pk(a.x, bq.x);
            d[36]  = bf16pk(a.y, bq.y);
            d[72]  = bf16pk(a.z, bq.z);
            d[108] = bf16pk(a.w, bq.w);
        }
    }
    f32x4 acc[16];
#pragma unroll
    for (int nt = 0; nt < 16; ++nt) acc[nt] = (f32x4)(0.f);
    __syncthreads();

    const unsigned short* wrow = Wb + ((size_t)b * NN + tok0 + w * 16 + n16) * SS;
#pragma unroll
    for (int ks = 0; ks < 2; ++ks) {
        union { uint4 u; s16x8 s; } av;
        av.u = *((const uint4*)(wrow + ks * 32 + quad * 8));
#pragma unroll
        for (int nt = 0; nt < 16; ++nt) {
            union { uint4 u; s16x8 s; } bv;
            bv.u = *((const uint4*)(s4t + (nt * 16 + n16) * 36 + ks * 16 + quad * 4));
            acc[nt] = __builtin_amdgcn_mfma_f32_16x16x32_bf16(av.s, bv.s, acc[nt], 0, 0, 0);
        }
    }
    const size_t rb = ((size_t)b * NN + tok0 + w * 16 + quad * 4) * HH;
#pragma unroll
    for (int r = 0; r < 4; ++r) {
#pragma unroll
        for (int nt = 0; nt < 16; ++nt) {
            const size_t o = rb + (size_t)r * HH + nt * 16 + n16;
            out[o] = acc[nt][r] + x[o];
        }
    }
}

// ---------------------------------------------------------------------------
extern "C" void kernel_launch(void* const* d_in, const int* in_sizes, int n_in,
                              void* d_out, int out_size, void* d_ws, size_t ws_size,
                              hipStream_t stream)
{
    const float* x         = (const float*)d_in[0];
    const float* sq_w      = (const float*)d_in[1];
    const float* sq_b      = (const float*)d_in[2];
    const float* eid_state = (const float*)d_in[3];
    const float* eid_gw    = (const float*)d_in[4];
    const float* eid_gb    = (const float*)d_in[5];
    const float* in_w      = (const float*)d_in[6];
    const float* in_b      = (const float*)d_in[7];
    const float* out_w     = (const float*)d_in[8];
    const float* out_b     = (const float*)d_in[9];
    const float* n1_g      = (const float*)d_in[10];
    const float* n1_b      = (const float*)d_in[11];
    const float* n2_g      = (const float*)d_in[12];
    const float* n2_b      = (const float*)d_in[13];
    const float* f1_w      = (const float*)d_in[14];
    const float* f1_b      = (const float*)d_in[15];
    const float* f2_w      = (const float*)d_in[16];
    const float* f2_b      = (const float*)d_in[17];

    float* ws = (float*)d_ws;
    unsigned short* Wb = (unsigned short*)ws;      // [B][N][S] bf16 = 4194304 floats
    float* partial = ws + 4194304;                 // [B][128][S][H] 8388608
    float* st0     = partial + 8388608;            // [B][S][H] 65536
    float* st2     = st0 + 65536;
    float* qkv     = st2 + 65536;                  // [B][S][768] 196608
    float* ao      = qkv + 196608;                 // [B][S][H] 65536
    float* st3     = ao + 65536;
    float* h1      = st3 + 65536;                  // [B][S][1024] 262144
    float* st4     = h1 + 262144;                  // [B][S][H] 65536
    float* out     = (float*)d_out;

    hipLaunchKernelGGL(k1a_scores, dim3(BB * 256), dim3(256), 0, stream,
                       x, sq_w, sq_b, Wb);
    hipLaunchKernelGGL(k1b_pool, dim3(BB * 128), dim3(256), 0, stream,
                       x, Wb, partial);
    hipLaunchKernelGGL(k1c_reduce, dim3(256), dim3(256), 0, stream, partial, st0);
    hipLaunchKernelGGL(mk1a_gate, dim3(SS), dim3(256), 0, stream,
                       st0, eid_state, eid_gw, eid_gb, st2);
    hipLaunchKernelGGL(mk1b_qkv, dim3(SS * 3), dim3(256), 0, stream,
                       st2, in_w, in_b, qkv);
    hipLaunchKernelGGL(mk2_attn, dim3(BB * NHH), dim3(64), 0, stream, qkv, ao);
    hipLaunchKernelGGL(mk3_outln, dim3(SS), dim3(256), 0, stream,
                       ao, out_w, out_b, st2, n1_g, n1_b, st3);
    hipLaunchKernelGGL(mk4_ffn1, dim3(SS * 4), dim3(256), 0, stream,
                       st3, f1_w, f1_b, h1);
    hipLaunchKernelGGL(mk5_ffn2, dim3(SS), dim3(256), 0, stream,
                       h1, f2_w, f2_b, st3, n2_g, n2_b, st4);
    hipLaunchKernelGGL(k3_decode, dim3(BB * 512), dim3(256), 0, stream,
                       Wb, st4, x, out);
}